// Round 1
// baseline (274.550 us; speedup 1.0000x reference)
//
#include <hip/hip_runtime.h>
#include <math.h>

// Problem constants (B=4, S=4096, D=2048, E=64, K=8)
#define NTOK   16384      // B*S
#define DDIM   2048
#define NE     64
#define TOPK   8

#define THREADS 512
#define NWAVE   8
#define TOKPB   64        // tokens per block
#define BK      128       // K-chunk staged per iteration
#define KSLICE  (BK / NWAVE)   // 16 k per wave per chunk

// scoreBuf swizzle: logical [t][e] stored at t*67 + (e ^ (t>>3)); bijective,
// spreads the 8x8-lane-grid atomic pattern across banks.
#define SBIDX(t,e) ((t)*67 + ((e) ^ ((t) >> 3)))

__global__ __launch_bounds__(THREADS) void gate_kernel(
    const float* __restrict__ x, const float* __restrict__ W,
    const float* __restrict__ b, float* __restrict__ out)
{
    // 64 KiB LDS: ldsX = smem[0..8191]  ([BK][64] k-major, transposed x tile)
    //             ldsW = smem[8192..16383] ([BK][64], same layout as global)
    // scoreBuf [64][67-swizzled] aliases smem[0..4283] after the main loop.
    __shared__ float smem[16384];

    const int tid  = threadIdx.x;
    const int wave = tid >> 6;
    const int lane = tid & 63;
    const int tg   = lane >> 3;   // token group 0..7 -> tokens tg*8..tg*8+7
    const int eg   = lane & 7;    // expert group 0..7 -> experts eg*8..eg*8+7
    const int tok0 = blockIdx.x * TOKPB;

    float acc[8][8];
#pragma unroll
    for (int i = 0; i < 8; ++i)
#pragma unroll
        for (int j = 0; j < 8; ++j) acc[i][j] = 0.f;

    const int kw0 = wave * KSLICE;
    // staging map for x: t = tid>>3 (8 lanes per row -> 128B coalesced global
    // reads), k4 = (tid&7) + jj*8
    const int st_t  = tid >> 3;
    const int st_k4 = tid & 7;

    for (int c = 0; c < DDIM / BK; ++c) {
        const int kc = c * BK;
        __syncthreads();   // previous chunk fully consumed
        // ---- stage x[64 tokens][BK] transposed into ldsX[k][t] ----
#pragma unroll
        for (int jj = 0; jj < 4; ++jj) {
            const int k4 = st_k4 + jj * 8;            // 0..31
            const float4 v = *(const float4*)&x[(size_t)(tok0 + st_t) * DDIM + kc + k4 * 4];
            smem[(k4 * 4 + 0) * 64 + st_t] = v.x;
            smem[(k4 * 4 + 1) * 64 + st_t] = v.y;
            smem[(k4 * 4 + 2) * 64 + st_t] = v.z;
            smem[(k4 * 4 + 3) * 64 + st_t] = v.w;
        }
        // ---- stage W[kc..kc+BK][64] linearly ----
        {
            const float4* Wg = (const float4*)&W[(size_t)kc * NE];
#pragma unroll
            for (int jj = 0; jj < 4; ++jj) {
                const int slot = tid + jj * THREADS;  // 0..2047
                *(float4*)&smem[8192 + slot * 4] = Wg[slot];
            }
        }
        __syncthreads();
        // ---- compute: this wave's k slice, 8x8 outer product per lane ----
#pragma unroll
        for (int kk = 0; kk < KSLICE; ++kk) {
            const int k = kw0 + kk;
            const float4 xa = *(const float4*)&smem[k * 64 + tg * 8];
            const float4 xb = *(const float4*)&smem[k * 64 + tg * 8 + 4];
            const float4 wa = *(const float4*)&smem[8192 + k * 64 + eg * 8];
            const float4 wb = *(const float4*)&smem[8192 + k * 64 + eg * 8 + 4];
            const float xs[8] = {xa.x, xa.y, xa.z, xa.w, xb.x, xb.y, xb.z, xb.w};
            const float ws[8] = {wa.x, wa.y, wa.z, wa.w, wb.x, wb.y, wb.z, wb.w};
#pragma unroll
            for (int i = 0; i < 8; ++i)
#pragma unroll
                for (int j = 0; j < 8; ++j)
                    acc[i][j] = fmaf(xs[i], ws[j], acc[i][j]);
        }
    }

    // ---- cross-wave reduction into swizzled scoreBuf (aliases ldsX) ----
    __syncthreads();
    for (int s = tid; s < 64 * 67; s += THREADS) smem[s] = 0.f;
    __syncthreads();
#pragma unroll
    for (int i = 0; i < 8; ++i)
#pragma unroll
        for (int j = 0; j < 8; ++j) {
            const int t = tg * 8 + i;
            const int e = eg * 8 + j;
            atomicAdd(&smem[SBIDX(t, e)], acc[i][j]);
        }
    __syncthreads();

    float* out_g   = out;                       // [16384][8]
    float* out_idx = out + (size_t)NTOK * TOPK; // [16384][8] (as float)
    float* out_s   = out + (size_t)NTOK * TOPK * 2; // [16384][64]

    // ---- sigmoid + store scores; overwrite scoreBuf with sigmoid ----
#pragma unroll
    for (int r = 0; r < 8; ++r) {
        const int flat = r * THREADS + tid;     // 0..4095
        const int t = flat >> 6;
        const int e = flat & 63;
        const float z = smem[SBIDX(t, e)] + b[e];
        const float s = 1.f / (1.f + expf(-z));
        out_s[(size_t)tok0 * NE + flat] = s;
        smem[SBIDX(t, e)] = s;
    }
    __syncthreads();

    // ---- top-8 per token (selection on sigmoid values; strict > picks the
    // first/lowest index on ties, matching jax.lax.top_k) ----
    if (tid < TOKPB) {
        const int t = tid;
        float gv[TOPK];
        int   gi[TOPK];
        float sum = 0.f;
#pragma unroll
        for (int j = 0; j < TOPK; ++j) {
            float best = -1.f;
            int bi = 0;
            for (int e = 0; e < NE; ++e) {
                const float v = smem[SBIDX(t, e)];
                if (v > best) { best = v; bi = e; }
            }
            gv[j] = best; gi[j] = bi; sum += best;
            smem[SBIDX(t, bi)] = -2.f;  // sigmoid in (0,1), so excluded
        }
        const float inv = 1.f / sum;
#pragma unroll
        for (int j = 0; j < TOPK; ++j) {
            out_g[(size_t)(tok0 + t) * TOPK + j]   = gv[j] * inv;
            out_idx[(size_t)(tok0 + t) * TOPK + j] = (float)gi[j];
        }
    }
}

extern "C" void kernel_launch(void* const* d_in, const int* in_sizes, int n_in,
                              void* d_out, int out_size, void* d_ws, size_t ws_size,
                              hipStream_t stream) {
    const float* x = (const float*)d_in[0];
    const float* W = (const float*)d_in[1];
    const float* b = (const float*)d_in[2];
    // d_in[3] is k (==8), compile-time constant here.
    float* out = (float*)d_out;
    gate_kernel<<<NTOK / TOKPB, THREADS, 0, stream>>>(x, W, b, out);
}